// Round 7
// baseline (229.177 us; speedup 1.0000x reference)
//
#include <hip/hip_runtime.h>

#define S_LEN 2048
#define DMODEL 768
#define NH 12
#define DHEAD 64
#define BATCH 4
#define MROWS (BATCH * S_LEN)  // 8192
#define NQKV 2304              // 3*DMODEL
#define NQK 1536               // packed Q+K row stride
#define LOG2E 1.4426950408889634f

using short8 = __attribute__((ext_vector_type(8))) short;
using f32x4  = __attribute__((ext_vector_type(4))) float;
using f32x16 = __attribute__((ext_vector_type(16))) float;

typedef const __attribute__((address_space(1))) void* gas_ptr;
typedef __attribute__((address_space(3))) void* las_ptr;

__device__ __forceinline__ void gl2lds16(const void* g, void* l) {
  __builtin_amdgcn_global_load_lds((gas_ptr)(unsigned long long)g,
                                   (las_ptr)(unsigned int)(unsigned long long)l,
                                   16, 0, 0);
}

// 2^x via raw v_exp_f32
__device__ __forceinline__ float fexp2(float x) {
  float r;
  asm("v_exp_f32 %0, %1" : "=v"(r) : "v"(x));
  return r;
}

// packed f32x2 -> bf16x2 (RNE), lo in [15:0]
__device__ __forceinline__ unsigned cvtpk(float lo, float hi) {
  unsigned r;
  asm("v_cvt_pk_bf16_f32 %0, %1, %2" : "=v"(r) : "v"(lo), "v"(hi));
  return r;
}

// swap a.hi32lanes <-> b.lo32lanes
__device__ __forceinline__ void plswap(unsigned &a, unsigned &b) {
  asm("v_permlane32_swap_b32 %0, %1" : "+v"(a), "+v"(b));
}

// Fused prep: fp32->bf16 for X and the 3 W's, mask -> (mask-10)*log2e
__global__ __launch_bounds__(256) void prep_kernel(
    const float* __restrict__ hs, const float* __restrict__ Wq,
    const float* __restrict__ Wk, const float* __restrict__ Wv,
    const float* __restrict__ mask,
    unsigned short* __restrict__ Xb, unsigned short* __restrict__ Wall,
    float* __restrict__ mask2)
{
  const int NX = MROWS * DMODEL / 4;
  const int NW = DMODEL * DMODEL / 4;
  const int NM = (BATCH * S_LEN) / 4;
  int i = blockIdx.x * 256 + threadIdx.x;
  if (i < NX) {
    float4 f = ((const float4*)hs)[i];
    uint2 o = { cvtpk(f.x, f.y), cvtpk(f.z, f.w) };
    ((uint2*)Xb)[i] = o;
  } else if (i < NX + 3 * NW) {
    int j = i - NX;
    int sec = j / NW, r = j - sec * NW;
    const float* src = (sec == 0) ? Wq : (sec == 1) ? Wk : Wv;
    float4 f = ((const float4*)src)[r];
    uint2 o = { cvtpk(f.x, f.y), cvtpk(f.z, f.w) };
    ((uint2*)(Wall + (size_t)sec * DMODEL * DMODEL))[r] = o;
  } else if (i < NX + 3 * NW + NM) {
    int r = i - NX - 3 * NW;
    float4 m = ((const float4*)mask)[r];
    float4 o = { (m.x - 10.f) * LOG2E, (m.y - 10.f) * LOG2E,
                 (m.z - 10.f) * LOG2E, (m.w - 10.f) * LOG2E };
    ((float4*)mask2)[r] = o;
  }
}

// Out: Q/K cols -> QK [8192][1536] (Q pre-scaled 1/8*log2e);
//      V cols   -> Vt [b][h][d][s] directly (v_transpose fused).
// XCD-swizzled 1-D grid.
__global__ __launch_bounds__(256) void qkv_gemm(
    const unsigned short* __restrict__ Xb,   // [8192][768]
    const unsigned short* __restrict__ Wall, // [2304][768]
    const float* __restrict__ bq,
    const float* __restrict__ bk,
    const float* __restrict__ bv,
    unsigned short* __restrict__ QK,         // [8192][1536]
    unsigned short* __restrict__ Vt)         // [4*12*64][2048]
{
  __shared__ __align__(16) short As[128][64];
  __shared__ __align__(16) short Bs[128][64];

  // grid = 1152 = 8 xcd * 8 mlocal * 18 n
  int gid = blockIdx.x;
  int x = gid & 7;
  int j = gid >> 3;
  int mloc = j / 18;
  int ntile = j - mloc * 18;
  int m0 = (x * 8 + mloc) * 128;
  int n0 = ntile * 128;

  int t = threadIdx.x;
  int w = t >> 6, lane = t & 63, lg = lane >> 4, lc = lane & 15;
  int wr = (w >> 1) * 64, wc = (w & 1) * 64;

  int srow = lane >> 3;
  int schunk = (lane & 7) ^ srow;

  f32x4 acc[4][4] = {};

  for (int k0 = 0; k0 < DMODEL; k0 += 64) {
    __syncthreads();
    for (int it = 0; it < 4; ++it) {
      int rb = w * 32 + it * 8;
      int r = rb + srow;
      gl2lds16(&Xb[(size_t)(m0 + r) * DMODEL + k0 + schunk * 8], &As[rb][0]);
      gl2lds16(&Wall[(size_t)(n0 + r) * DMODEL + k0 + schunk * 8], &Bs[rb][0]);
    }
    __syncthreads();
    for (int ks = 0; ks < 2; ++ks) {
      short8 a[4], b[4];
      for (int mt = 0; mt < 4; ++mt)
        a[mt] = *(const short8*)&As[wr + mt * 16 + lc][(((ks * 4 + lg) ^ (lc & 7))) * 8];
      for (int nt = 0; nt < 4; ++nt)
        b[nt] = *(const short8*)&Bs[wc + nt * 16 + lc][(((ks * 4 + lg) ^ (lc & 7))) * 8];
      for (int mt = 0; mt < 4; ++mt)
        for (int nt = 0; nt < 4; ++nt)
          acc[mt][nt] = __builtin_amdgcn_mfma_f32_16x16x32_bf16(a[mt], b[nt], acc[mt][nt], 0, 0, 0);
    }
  }

  if (n0 < 1536) {
    // ---- Q/K epilogue: row-major 2B stores into packed QK ----
    for (int nt = 0; nt < 4; ++nt) {
      int col = n0 + wc + nt * 16 + lc;
      float bb = (col < 768) ? bq[col] : bk[col - 768];
      float sc = (col < 768) ? (0.125f * LOG2E) : 1.0f;
      for (int mt = 0; mt < 4; ++mt) {
        int row = m0 + wr + mt * 16 + lg * 4;
        for (int i = 0; i < 4; ++i) {
          float v = (acc[mt][nt][i] + bb) * sc;
          QK[(size_t)(row + i) * NQK + col] = (unsigned short)cvtpk(v, v);
        }
      }
    }
  } else {
    // ---- V epilogue: write transposed directly to Vt [b][h][d][s] ----
    int b2 = m0 >> 11;
    for (int nt = 0; nt < 4; ++nt) {
      int col = n0 + wc + nt * 16 + lc - 1536;  // 0..767 within V
      int h2 = col >> 6, dd = col & 63;
      float bb = bv[col];
      size_t vbase = ((size_t)(b2 * NH + h2) * DHEAD + dd) * S_LEN;
      for (int mt = 0; mt < 4; ++mt) {
        int row = m0 + wr + mt * 16 + lg * 4;
        int s = row & (S_LEN - 1);
        float v0 = acc[mt][nt][0] + bb;
        float v1 = acc[mt][nt][1] + bb;
        float v2 = acc[mt][nt][2] + bb;
        float v3 = acc[mt][nt][3] + bb;
        uint2 d2 = { cvtpk(v0, v1), cvtpk(v2, v3) };
        *(uint2*)&Vt[vbase + s] = d2;
      }
    }
  }
}

// Flash attention — R6 92/90us body, now split-KV capable (NS splits over the
// key dimension). Fixed-max softmax => partials combine exactly:
// out = (sum_ks o_ks) / (sum_ks l_ks). NS==1 path identical to R6.
__global__ __launch_bounds__(256, 4) void flash_attn(
    const unsigned short* __restrict__ QK,   // [8192][1536]; Q pre-scaled log2e/8
    const unsigned short* __restrict__ Vt,   // [48*64][2048]
    const float* __restrict__ mask2,         // (mask-10)*log2e, [B][S]
    float* __restrict__ out,                 // [B][S][768]
    float* __restrict__ opart,               // [NS][8192][768] unnormalized
    float* __restrict__ lpart,               // [NS][B*NH][S]
    int NS)
{
  // grid = 8 xcd * 6 glocal * 16 qt * NS ; (b,h) pinned to one xcd
  int gid = blockIdx.x;
  int x = gid & 7;
  int j = gid >> 3;
  int ks = (NS == 2) ? (j & 1) : 0;
  if (NS == 2) j >>= 1;
  int gloc = j >> 4;
  int qt = j & 15;
  int g = gloc * 8 + x;
  int h = g % NH;
  int b = g / NH;
  int kt0 = ks * (32 / NS);
  int ktend = kt0 + 32 / NS;

  __shared__ __align__(16) short Ks[2][64][64];    // swizzled [key][d]
  __shared__ __align__(16) short Vts[2][64][64];   // swizzled [d][key]

  int t = threadIdx.x, w = t >> 6, lane = t & 63;
  int m31 = lane & 31, hf = lane >> 5;
  int q0 = qt * 128;
  int srow = lane >> 3;
  int schunk = (lane & 7) ^ srow;

  // Q B-frags: loop-invariant, direct from global. B[k=d][n=q]: n=m31, k=8*hf+j
  short8 qf[4];
  {
    size_t qrow = (size_t)(b * S_LEN + q0 + w * 32 + m31) * NQK + h * DHEAD;
#pragma unroll
    for (int kk = 0; kk < 4; ++kk)
      qf[kk] = *(const short8*)&QK[qrow + kk * 16 + hf * 8];
  }

  float lsum = 0.f;
  f32x16 o[2] = {};
  size_t vtbase = (size_t)((b * NH + h) * DHEAD) * S_LEN;
  size_t kbase0 = (size_t)(b * S_LEN) * NQK + 768 + h * DHEAD;
  const float* mrow = mask2 + (size_t)b * S_LEN;

  // prologue: stage tile kt0 into buffer 0
#pragma unroll
  for (int it = 0; it < 2; ++it) {
    int rb = w * 16 + it * 8;
    int r = rb + srow;
    gl2lds16(&QK[kbase0 + (size_t)(kt0 * 64 + r) * NQK + schunk * 8], &Ks[0][rb][0]);
    gl2lds16(&Vt[vtbase + (size_t)r * S_LEN + kt0 * 64 + schunk * 8], &Vts[0][rb][0]);
  }

  int buf = 0;
  for (int kt = kt0; kt < ktend; ++kt) {
    int k0 = kt * 64;
    __syncthreads();  // tile kt resident (vmcnt drained); prev compute done

    // prefetch next tile into buf^1 (clamped redundant reload on last iter)
    {
      int ktn = (kt + 1 < ktend) ? (kt + 1) : kt;
      int k0n = ktn * 64;
#pragma unroll
      for (int it = 0; it < 2; ++it) {
        int rb = w * 16 + it * 8;
        int r = rb + srow;
        gl2lds16(&QK[kbase0 + (size_t)(k0n + r) * NQK + schunk * 8], &Ks[buf ^ 1][rb][0]);
        gl2lds16(&Vt[vtbase + (size_t)r * S_LEN + k0n + schunk * 8], &Vts[buf ^ 1][rb][0]);
      }
    }

    // S^T[key][q] = K·Q^T
    f32x16 s[2] = {};
    __builtin_amdgcn_s_setprio(1);
#pragma unroll
    for (int kk = 0; kk < 4; ++kk)
#pragma unroll
      for (int mt = 0; mt < 2; ++mt) {
        int r = mt * 32 + m31;
        short8 ak = *(const short8*)&Ks[buf][r][((kk * 2 + hf) ^ (r & 7)) * 8];
        s[mt] = __builtin_amdgcn_mfma_f32_32x32x16_bf16(ak, qf[kk], s[mt], 0, 0, 0);
      }
    __builtin_amdgcn_s_setprio(0);

    // p = 2^(s + mask2); key = 32mt + 8g + 4hf + i ; q = m31
    unsigned pw[2][4][2];
#pragma unroll
    for (int mt = 0; mt < 2; ++mt)
#pragma unroll
      for (int gg = 0; gg < 4; ++gg) {
        float4 mv = *(const float4*)&mrow[k0 + mt * 32 + gg * 8 + hf * 4];
        float p0 = fexp2(s[mt][gg * 4 + 0] + mv.x);
        float p1 = fexp2(s[mt][gg * 4 + 1] + mv.y);
        float p2 = fexp2(s[mt][gg * 4 + 2] + mv.z);
        float p3 = fexp2(s[mt][gg * 4 + 3] + mv.w);
        lsum += (p0 + p1) + (p2 + p3);
        pw[mt][gg][0] = cvtpk(p0, p1);
        pw[mt][gg][1] = cvtpk(p2, p3);
      }

    // PV A-frags via permlane32_swap; O[q][d] += P·V
#pragma unroll
    for (int mt = 0; mt < 2; ++mt)
#pragma unroll
      for (int kk2 = 0; kk2 < 2; ++kk2) {
        unsigned a0 = pw[mt][2 * kk2][0], b0 = pw[mt][2 * kk2 + 1][0];
        unsigned a1 = pw[mt][2 * kk2][1], b1 = pw[mt][2 * kk2 + 1][1];
        plswap(a0, b0);
        plswap(a1, b1);
        union { unsigned u[4]; short8 v; } fr;
        fr.u[0] = a0; fr.u[1] = a1; fr.u[2] = b0; fr.u[3] = b1;
        int kk = mt * 2 + kk2;
        __builtin_amdgcn_s_setprio(1);
#pragma unroll
        for (int nt = 0; nt < 2; ++nt) {
          int r = nt * 32 + m31;
          short8 bvv = *(const short8*)&Vts[buf][r][((kk * 2 + hf) ^ (r & 7)) * 8];
          o[nt] = __builtin_amdgcn_mfma_f32_32x32x16_bf16(fr.v, bvv, o[nt], 0, 0, 0);
        }
        __builtin_amdgcn_s_setprio(0);
      }

    buf ^= 1;
  }

  // l for q=m31: own half + partner half
  lsum += __shfl_xor(lsum, 32, 64);

  if (NS == 1) {
    float inv = 1.0f / lsum;
    float lv[16];
#pragma unroll
    for (int r = 0; r < 16; ++r)
      lv[r] = __shfl(inv, (r & 3) + 8 * (r >> 2) + 4 * hf, 64);
    for (int nt = 0; nt < 2; ++nt)
      for (int r = 0; r < 16; ++r) {
        int qrow = (r & 3) + 8 * (r >> 2) + 4 * hf;
        int q = q0 + w * 32 + qrow;
        out[(size_t)(b * S_LEN + q) * DMODEL + h * DHEAD + nt * 32 + m31] = o[nt][r] * lv[r];
      }
  } else {
    float* op = opart + (size_t)ks * MROWS * DMODEL;
    for (int nt = 0; nt < 2; ++nt)
      for (int r = 0; r < 16; ++r) {
        int qrow = (r & 3) + 8 * (r >> 2) + 4 * hf;
        int q = q0 + w * 32 + qrow;
        op[(size_t)(b * S_LEN + q) * DMODEL + h * DHEAD + nt * 32 + m31] = o[nt][r];
      }
    if (hf == 0) {
      int q = q0 + w * 32 + m31;
      lpart[((size_t)ks * BATCH * NH + (b * NH + h)) * S_LEN + q] = lsum;
    }
  }
}

// out = (o0 + o1) / (l0 + l1)
__global__ __launch_bounds__(256) void combine_kernel(
    const float* __restrict__ op,   // [2][8192][768]
    const float* __restrict__ lp,   // [2][B*NH][S]
    float* __restrict__ out)
{
  const size_t OPSZ = (size_t)MROWS * DMODEL;
  const size_t LPSZ = (size_t)BATCH * NH * S_LEN;
  int i = blockIdx.x * 256 + threadIdx.x;      // f32x4 index over [8192][192]
  int row = i / 192;                            // b*S + s
  int cq = i - row * 192;                       // quad-col
  int h = cq >> 4;
  int b = row >> 11, s = row & (S_LEN - 1);
  size_t lidx = (size_t)(b * NH + h) * S_LEN + s;
  float l = lp[lidx] + lp[LPSZ + lidx];
  float inv = 1.0f / l;
  f32x4 a = *(const f32x4*)&op[(size_t)i * 4];
  f32x4 c = *(const f32x4*)&op[OPSZ + (size_t)i * 4];
  f32x4 r = { (a[0] + c[0]) * inv, (a[1] + c[1]) * inv,
              (a[2] + c[2]) * inv, (a[3] + c[3]) * inv };
  *(f32x4*)&out[(size_t)i * 4] = r;
}

extern "C" void kernel_launch(void* const* d_in, const int* in_sizes, int n_in,
                              void* d_out, int out_size, void* d_ws, size_t ws_size,
                              hipStream_t stream) {
  const float* hs   = (const float*)d_in[0];
  const float* mask = (const float*)d_in[1];
  const float* Wq   = (const float*)d_in[2];
  const float* bq   = (const float*)d_in[3];
  const float* Wk   = (const float*)d_in[4];
  const float* bk   = (const float*)d_in[5];
  const float* Wv   = (const float*)d_in[6];
  const float* bv   = (const float*)d_in[7];
  float* out = (float*)d_out;

  char* ws = (char*)d_ws;
  const size_t XB_BYTES   = (size_t)MROWS * DMODEL * 2;   // 12.58 MB
  const size_t QK_BYTES   = (size_t)MROWS * NQK * 2;      // 25.17 MB
  const size_t VT_BYTES   = (size_t)BATCH * NH * DHEAD * S_LEN * 2;  // 12.58 MB
  const size_t WALL_BYTES = (size_t)NQKV * DMODEL * 2;    // 3.54 MB
  const size_t M2_BYTES   = (size_t)BATCH * S_LEN * 4;
  unsigned short* Xb    = (unsigned short*)ws;
  unsigned short* QK    = (unsigned short*)(ws + XB_BYTES);
  unsigned short* Vtg   = (unsigned short*)(ws + XB_BYTES + QK_BYTES);
  unsigned short* Wall  = (unsigned short*)(ws + XB_BYTES + QK_BYTES + VT_BYTES);
  float*          mask2 = (float*)(ws + XB_BYTES + QK_BYTES + VT_BYTES + WALL_BYTES);

  size_t base = XB_BYTES + QK_BYTES + VT_BYTES + WALL_BYTES + M2_BYTES;
  base = (base + 255) & ~(size_t)255;
  const size_t OP_BYTES = 2 * (size_t)MROWS * DMODEL * 4;       // 50.3 MB
  const size_t LP_BYTES = 2 * (size_t)BATCH * NH * S_LEN * 4;   // 0.79 MB
  int NS = (ws_size >= base + OP_BYTES + LP_BYTES) ? 2 : 1;
  float* opart = (float*)(ws + base);
  float* lpart = (float*)(ws + base + OP_BYTES);

  const int NX = MROWS * DMODEL / 4;
  const int NW = DMODEL * DMODEL / 4;
  const int NM = (BATCH * S_LEN) / 4;
  int nprep = NX + 3 * NW + NM;
  prep_kernel<<<(nprep + 255) / 256, 256, 0, stream>>>(hs, Wq, Wk, Wv, mask, Xb, Wall, mask2);

  qkv_gemm<<<1152, 256, 0, stream>>>(Xb, Wall, bq, bk, bv, QK, Vtg);

  flash_attn<<<NS == 2 ? 1536 : 768, 256, 0, stream>>>(QK, Vtg, mask2, out, opart, lpart, NS);

  if (NS == 2)
    combine_kernel<<<MROWS * DMODEL / 4 / 256, 256, 0, stream>>>(opart, lpart, out);
}

// Round 8
// 219.628 us; speedup vs baseline: 1.0435x; 1.0435x over previous
//
#include <hip/hip_runtime.h>

#define S_LEN 2048
#define DMODEL 768
#define NH 12
#define DHEAD 64
#define BATCH 4
#define MROWS (BATCH * S_LEN)  // 8192
#define NQKV 2304              // 3*DMODEL
#define NQK 1536               // packed Q+K row stride
#define LOG2E 1.4426950408889634f

using short8 = __attribute__((ext_vector_type(8))) short;
using f32x4  = __attribute__((ext_vector_type(4))) float;
using f32x16 = __attribute__((ext_vector_type(16))) float;

typedef const __attribute__((address_space(1))) void* gas_ptr;
typedef __attribute__((address_space(3))) void* las_ptr;

__device__ __forceinline__ void gl2lds16(const void* g, void* l) {
  __builtin_amdgcn_global_load_lds((gas_ptr)(unsigned long long)g,
                                   (las_ptr)(unsigned int)(unsigned long long)l,
                                   16, 0, 0);
}

// 2^x via raw v_exp_f32
__device__ __forceinline__ float fexp2(float x) {
  float r;
  asm("v_exp_f32 %0, %1" : "=v"(r) : "v"(x));
  return r;
}

// packed f32x2 -> bf16x2 (RNE), lo in [15:0]
__device__ __forceinline__ unsigned cvtpk(float lo, float hi) {
  unsigned r;
  asm("v_cvt_pk_bf16_f32 %0, %1, %2" : "=v"(r) : "v"(lo), "v"(hi));
  return r;
}

// swap a.hi32lanes <-> b.lo32lanes
__device__ __forceinline__ void plswap(unsigned &a, unsigned &b) {
  asm("v_permlane32_swap_b32 %0, %1" : "+v"(a), "+v"(b));
}

// Fused prep: fp32->bf16 for X and the 3 W's, mask -> (mask-10)*log2e
__global__ __launch_bounds__(256) void prep_kernel(
    const float* __restrict__ hs, const float* __restrict__ Wq,
    const float* __restrict__ Wk, const float* __restrict__ Wv,
    const float* __restrict__ mask,
    unsigned short* __restrict__ Xb, unsigned short* __restrict__ Wall,
    float* __restrict__ mask2)
{
  const int NX = MROWS * DMODEL / 4;
  const int NW = DMODEL * DMODEL / 4;
  const int NM = (BATCH * S_LEN) / 4;
  int i = blockIdx.x * 256 + threadIdx.x;
  if (i < NX) {
    float4 f = ((const float4*)hs)[i];
    uint2 o = { cvtpk(f.x, f.y), cvtpk(f.z, f.w) };
    ((uint2*)Xb)[i] = o;
  } else if (i < NX + 3 * NW) {
    int j = i - NX;
    int sec = j / NW, r = j - sec * NW;
    const float* src = (sec == 0) ? Wq : (sec == 1) ? Wk : Wv;
    float4 f = ((const float4*)src)[r];
    uint2 o = { cvtpk(f.x, f.y), cvtpk(f.z, f.w) };
    ((uint2*)(Wall + (size_t)sec * DMODEL * DMODEL))[r] = o;
  } else if (i < NX + 3 * NW + NM) {
    int r = i - NX - 3 * NW;
    float4 m = ((const float4*)mask)[r];
    float4 o = { (m.x - 10.f) * LOG2E, (m.y - 10.f) * LOG2E,
                 (m.z - 10.f) * LOG2E, (m.w - 10.f) * LOG2E };
    ((float4*)mask2)[r] = o;
  }
}

// Out: Q/K cols -> QK [8192][1536] (Q pre-scaled 1/8*log2e);
//      V cols   -> Vt [b][h][d][s] directly (v_transpose fused).
// XCD-swizzled 1-D grid. QK epilogue: LDS-assembled coalesced 16B stores
// (reuses the 32KB staging buffer after the last K-step barrier).
__global__ __launch_bounds__(256) void qkv_gemm(
    const unsigned short* __restrict__ Xb,   // [8192][768]
    const unsigned short* __restrict__ Wall, // [2304][768]
    const float* __restrict__ bq,
    const float* __restrict__ bk,
    const float* __restrict__ bv,
    unsigned short* __restrict__ QK,         // [8192][1536]
    unsigned short* __restrict__ Vt)         // [4*12*64][2048]
{
  __shared__ __align__(16) short SM[2][128][64];
#define As SM[0]
#define Bs SM[1]

  // grid = 1152 = 8 xcd * 8 mlocal * 18 n
  int gid = blockIdx.x;
  int x = gid & 7;
  int j = gid >> 3;
  int mloc = j / 18;
  int ntile = j - mloc * 18;
  int m0 = (x * 8 + mloc) * 128;
  int n0 = ntile * 128;

  int t = threadIdx.x;
  int w = t >> 6, lane = t & 63, lg = lane >> 4, lc = lane & 15;
  int wr = (w >> 1) * 64, wc = (w & 1) * 64;

  int srow = lane >> 3;
  int schunk = (lane & 7) ^ srow;

  f32x4 acc[4][4] = {};

  for (int k0 = 0; k0 < DMODEL; k0 += 64) {
    __syncthreads();
    for (int it = 0; it < 4; ++it) {
      int rb = w * 32 + it * 8;
      int r = rb + srow;
      gl2lds16(&Xb[(size_t)(m0 + r) * DMODEL + k0 + schunk * 8], &As[rb][0]);
      gl2lds16(&Wall[(size_t)(n0 + r) * DMODEL + k0 + schunk * 8], &Bs[rb][0]);
    }
    __syncthreads();
    for (int ks = 0; ks < 2; ++ks) {
      short8 a[4], b[4];
      for (int mt = 0; mt < 4; ++mt)
        a[mt] = *(const short8*)&As[wr + mt * 16 + lc][(((ks * 4 + lg) ^ (lc & 7))) * 8];
      for (int nt = 0; nt < 4; ++nt)
        b[nt] = *(const short8*)&Bs[wc + nt * 16 + lc][(((ks * 4 + lg) ^ (lc & 7))) * 8];
      for (int mt = 0; mt < 4; ++mt)
        for (int nt = 0; nt < 4; ++nt)
          acc[mt][nt] = __builtin_amdgcn_mfma_f32_16x16x32_bf16(a[mt], b[nt], acc[mt][nt], 0, 0, 0);
    }
  }

  if (n0 < 1536) {
    // ---- Q/K epilogue: assemble tile in LDS (swizzled), store coalesced ----
    __syncthreads();  // all waves done reading As/Bs
    short* S2 = &SM[0][0][0];  // [128][128] bf16 view of the 32KB
    for (int nt = 0; nt < 4; ++nt) {
      int col = n0 + wc + nt * 16 + lc;
      float bb = (col < 768) ? bq[col] : bk[col - 768];
      float sc = (col < 768) ? (0.125f * LOG2E) : 1.0f;
      int col_l = wc + nt * 16 + lc;
      for (int mt = 0; mt < 4; ++mt) {
        int rbase = wr + mt * 16 + lg * 4;
        for (int i = 0; i < 4; ++i) {
          float v = (acc[mt][nt][i] + bb) * sc;
          // XOR-swizzle: row's bits[3:2] (== lg) flip col bits[5:4] -> the 4
          // lg row-groups hit 4 disjoint 8-bank sets (conflict-free).
          S2[(rbase + i) * 128 + (col_l ^ (lg << 4))] =
              (short)(unsigned short)cvtpk(v, v);
        }
      }
    }
    __syncthreads();
    for (int j2 = 0; j2 < 8; ++j2) {
      int idx = j2 * 256 + t;          // over 128 rows x 16 chunks(16B)
      int row = idx >> 4, c = idx & 15;
      int kx = ((row >> 2) & 3) << 4;  // matches writer's (lg<<4)
      short8 v = *(const short8*)&S2[row * 128 + ((c * 8) ^ kx)];
      *(short8*)&QK[(size_t)(m0 + row) * NQK + n0 + c * 8] = v;
    }
  } else {
    // ---- V epilogue: write transposed directly to Vt [b][h][d][s] ----
    int b2 = m0 >> 11;
    for (int nt = 0; nt < 4; ++nt) {
      int col = n0 + wc + nt * 16 + lc - 1536;  // 0..767 within V
      int h2 = col >> 6, dd = col & 63;
      float bb = bv[col];
      size_t vbase = ((size_t)(b2 * NH + h2) * DHEAD + dd) * S_LEN;
      for (int mt = 0; mt < 4; ++mt) {
        int row = m0 + wr + mt * 16 + lg * 4;
        int s = row & (S_LEN - 1);
        float v0 = acc[mt][nt][0] + bb;
        float v1 = acc[mt][nt][1] + bb;
        float v2 = acc[mt][nt][2] + bb;
        float v3 = acc[mt][nt][3] + bb;
        uint2 d2 = { cvtpk(v0, v1), cvtpk(v2, v3) };
        *(uint2*)&Vt[vbase + s] = d2;
      }
    }
  }
#undef As
#undef Bs
}

// Flash attention — R6-verified 90us body, XCD-swizzled 1-D grid
// (FETCH 18.6MB, L2-resident K/V). Split-KV reverted (R7: null).
__global__ __launch_bounds__(256, 4) void flash_attn(
    const unsigned short* __restrict__ QK,   // [8192][1536]; Q pre-scaled log2e/8
    const unsigned short* __restrict__ Vt,   // [48*64][2048]
    const float* __restrict__ mask2,         // (mask-10)*log2e, [B][S]
    float* __restrict__ out)                 // [B][S][768]
{
  // grid = 768 = 8 xcd * 6 glocal * 16 qt ; group g=(b,h) pinned to one xcd
  int gid = blockIdx.x;
  int x = gid & 7;
  int j = gid >> 3;
  int gloc = j >> 4;
  int qt = j & 15;
  int g = gloc * 8 + x;
  int h = g % NH;
  int b = g / NH;

  __shared__ __align__(16) short Ks[2][64][64];    // swizzled [key][d]
  __shared__ __align__(16) short Vts[2][64][64];   // swizzled [d][key]

  int t = threadIdx.x, w = t >> 6, lane = t & 63;
  int m31 = lane & 31, hf = lane >> 5;  // 32-row index, half
  int q0 = qt * 128;
  int srow = lane >> 3;
  int schunk = (lane & 7) ^ srow;

  // Q B-frags: loop-invariant, direct from global. B[k=d][n=q]: n=m31, k=8*hf+j
  short8 qf[4];
  {
    size_t qrow = (size_t)(b * S_LEN + q0 + w * 32 + m31) * NQK + h * DHEAD;
#pragma unroll
    for (int kk = 0; kk < 4; ++kk)
      qf[kk] = *(const short8*)&QK[qrow + kk * 16 + hf * 8];
  }

  float lsum = 0.f;                    // l for q = m31 (this lane's column)
  f32x16 o[2] = {};                    // O tiles: d in {nt*32 + m31}
  size_t vtbase = (size_t)((b * NH + h) * DHEAD) * S_LEN;
  size_t kbase0 = (size_t)(b * S_LEN) * NQK + 768 + h * DHEAD;
  const float* mrow = mask2 + (size_t)b * S_LEN;

  // prologue: stage tile 0 into buffer 0
#pragma unroll
  for (int it = 0; it < 2; ++it) {
    int rb = w * 16 + it * 8;
    int r = rb + srow;
    gl2lds16(&QK[kbase0 + (size_t)r * NQK + schunk * 8], &Ks[0][rb][0]);
    gl2lds16(&Vt[vtbase + (size_t)r * S_LEN + schunk * 8], &Vts[0][rb][0]);
  }

  int buf = 0;
  for (int kt = 0; kt < S_LEN / 64; ++kt) {
    int k0 = kt * 64;
    __syncthreads();  // tile kt resident (vmcnt drained); prev compute done

    // prefetch next tile into buf^1 (clamped redundant reload on last iter)
    {
      int ktn = (kt + 1 < S_LEN / 64) ? (kt + 1) : kt;
      int k0n = ktn * 64;
#pragma unroll
      for (int it = 0; it < 2; ++it) {
        int rb = w * 16 + it * 8;
        int r = rb + srow;
        gl2lds16(&QK[kbase0 + (size_t)(k0n + r) * NQK + schunk * 8], &Ks[buf ^ 1][rb][0]);
        gl2lds16(&Vt[vtbase + (size_t)r * S_LEN + k0n + schunk * 8], &Vts[buf ^ 1][rb][0]);
      }
    }

    // S^T[key][q] = K·Q^T: A=K rows (2 mt tiles of 32 keys), B=qf. k-dim=64 (4 kk)
    f32x16 s[2] = {};
    __builtin_amdgcn_s_setprio(1);
#pragma unroll
    for (int kk = 0; kk < 4; ++kk)
#pragma unroll
      for (int mt = 0; mt < 2; ++mt) {
        int r = mt * 32 + m31;
        short8 ak = *(const short8*)&Ks[buf][r][((kk * 2 + hf) ^ (r & 7)) * 8];
        s[mt] = __builtin_amdgcn_mfma_f32_32x32x16_bf16(ak, qf[kk], s[mt], 0, 0, 0);
      }
    __builtin_amdgcn_s_setprio(0);

    // p = 2^(s + mask2); key = 32mt + 8g + 4hf + i ; q = m31
    unsigned pw[2][4][2];
#pragma unroll
    for (int mt = 0; mt < 2; ++mt)
#pragma unroll
      for (int gg = 0; gg < 4; ++gg) {
        float4 mv = *(const float4*)&mrow[k0 + mt * 32 + gg * 8 + hf * 4];
        float p0 = fexp2(s[mt][gg * 4 + 0] + mv.x);
        float p1 = fexp2(s[mt][gg * 4 + 1] + mv.y);
        float p2 = fexp2(s[mt][gg * 4 + 2] + mv.z);
        float p3 = fexp2(s[mt][gg * 4 + 3] + mv.w);
        lsum += (p0 + p1) + (p2 + p3);
        pw[mt][gg][0] = cvtpk(p0, p1);  // keys 32mt+8g+4hf+{0,1}
        pw[mt][gg][1] = cvtpk(p2, p3);  // keys 32mt+8g+4hf+{2,3}
      }

    // Build PV A-frags via permlane32_swap; O[q][d] += P·V
#pragma unroll
    for (int mt = 0; mt < 2; ++mt)
#pragma unroll
      for (int kk2 = 0; kk2 < 2; ++kk2) {
        unsigned a0 = pw[mt][2 * kk2][0], b0 = pw[mt][2 * kk2 + 1][0];
        unsigned a1 = pw[mt][2 * kk2][1], b1 = pw[mt][2 * kk2 + 1][1];
        plswap(a0, b0);  // a0=[keys+0,1 | +8,9]   b0=[keys+4,5 | +12,13]
        plswap(a1, b1);  // a1=[keys+2,3 | +10,11] b1=[keys+6,7 | +14,15]
        union { unsigned u[4]; short8 v; } fr;
        fr.u[0] = a0; fr.u[1] = a1; fr.u[2] = b0; fr.u[3] = b1;
        int kk = mt * 2 + kk2;
        __builtin_amdgcn_s_setprio(1);
#pragma unroll
        for (int nt = 0; nt < 2; ++nt) {
          int r = nt * 32 + m31;
          short8 bvv = *(const short8*)&Vts[buf][r][((kk * 2 + hf) ^ (r & 7)) * 8];
          o[nt] = __builtin_amdgcn_mfma_f32_32x32x16_bf16(fr.v, bvv, o[nt], 0, 0, 0);
        }
        __builtin_amdgcn_s_setprio(0);
      }

    buf ^= 1;
  }

  // final l for q=m31: own half + partner half, once
  lsum += __shfl_xor(lsum, 32, 64);
  float inv = 1.0f / lsum;
  // broadcast inv to C-layout rows: row q = (r&3) + 8*(r>>2) + 4*hf
  float lv[16];
#pragma unroll
  for (int r = 0; r < 16; ++r)
    lv[r] = __shfl(inv, (r & 3) + 8 * (r >> 2) + 4 * hf, 64);

  for (int nt = 0; nt < 2; ++nt)
    for (int r = 0; r < 16; ++r) {
      int qrow = (r & 3) + 8 * (r >> 2) + 4 * hf;
      int q = q0 + w * 32 + qrow;
      out[(size_t)(b * S_LEN + q) * DMODEL + h * DHEAD + nt * 32 + m31] = o[nt][r] * lv[r];
    }
}

extern "C" void kernel_launch(void* const* d_in, const int* in_sizes, int n_in,
                              void* d_out, int out_size, void* d_ws, size_t ws_size,
                              hipStream_t stream) {
  const float* hs   = (const float*)d_in[0];
  const float* mask = (const float*)d_in[1];
  const float* Wq   = (const float*)d_in[2];
  const float* bq   = (const float*)d_in[3];
  const float* Wk   = (const float*)d_in[4];
  const float* bk   = (const float*)d_in[5];
  const float* Wv   = (const float*)d_in[6];
  const float* bv   = (const float*)d_in[7];
  float* out = (float*)d_out;

  char* ws = (char*)d_ws;
  const size_t XB_BYTES   = (size_t)MROWS * DMODEL * 2;   // 12.58 MB
  const size_t QK_BYTES   = (size_t)MROWS * NQK * 2;      // 25.17 MB
  const size_t VT_BYTES   = (size_t)BATCH * NH * DHEAD * S_LEN * 2;  // 12.58 MB
  const size_t WALL_BYTES = (size_t)NQKV * DMODEL * 2;    // 3.54 MB
  unsigned short* Xb    = (unsigned short*)ws;
  unsigned short* QK    = (unsigned short*)(ws + XB_BYTES);
  unsigned short* Vtg   = (unsigned short*)(ws + XB_BYTES + QK_BYTES);
  unsigned short* Wall  = (unsigned short*)(ws + XB_BYTES + QK_BYTES + VT_BYTES);
  float*          mask2 = (float*)(ws + XB_BYTES + QK_BYTES + VT_BYTES + WALL_BYTES);

  const int NX = MROWS * DMODEL / 4;
  const int NW = DMODEL * DMODEL / 4;
  const int NM = (BATCH * S_LEN) / 4;
  int nprep = NX + 3 * NW + NM;
  prep_kernel<<<(nprep + 255) / 256, 256, 0, stream>>>(hs, Wq, Wk, Wv, mask, Xb, Wall, mask2);

  qkv_gemm<<<1152, 256, 0, stream>>>(Xb, Wall, bq, bk, bv, QK, Vtg);

  flash_attn<<<768, 256, 0, stream>>>(QK, Vtg, mask2, out);
}